// Round 1
// baseline (5728.226 us; speedup 1.0000x reference)
//
#include <hip/hip_runtime.h>
#include <math.h>

#define N_NODES 50000
#define D 128
#define NE 800000

// ---------------------------------------------------------------------------
// degree: one atomicAdd per edge (runs once per call; degrees are
// feature-independent and shared by both layers)
// ---------------------------------------------------------------------------
__global__ void deg_kernel(const int* __restrict__ dst, float* __restrict__ deg, int E) {
    int e = blockIdx.x * blockDim.x + threadIdx.x;
    if (e < E) atomicAdd(&deg[dst[e]], 1.0f);
}

__global__ void inv_kernel(float* __restrict__ degA, float* __restrict__ degB, int n) {
    int i = blockIdx.x * blockDim.x + threadIdx.x;
    if (i < n) {
        degA[i] = 1.0f / fmaxf(degA[i], 1.0f);
        degB[i] = 1.0f / fmaxf(degB[i], 1.0f);
    }
}

// ---------------------------------------------------------------------------
// scatter: msg[dst] += feat[src].  32 threads per edge, float4 per thread.
// Gather reads are row-coalesced (32 lanes x 16B = 512B = one feature row).
// ---------------------------------------------------------------------------
__global__ void scatter_kernel(const float* __restrict__ feat,
                               const int* __restrict__ src,
                               const int* __restrict__ dst,
                               float* __restrict__ msg, int E) {
    int idx = blockIdx.x * blockDim.x + threadIdx.x;
    int e   = idx >> 5;
    int d4  = (idx & 31) << 2;      // float offset 0,4,...,124
    if (e >= E) return;
    int s = src[e];
    int t = dst[e];
    const float4 v = *reinterpret_cast<const float4*>(feat + (size_t)s * D + d4);
    float* mp = msg + (size_t)t * D + d4;
    atomicAdd(mp + 0, v.x);
    atomicAdd(mp + 1, v.y);
    atomicAdd(mp + 2, v.z);
    atomicAdd(mp + 3, v.w);
}

// ---------------------------------------------------------------------------
// fused layer GEMM:
//   out[i,:] = act( msgA[i,:]*invA[i] @ W0 + msgB[i,:]*invB[i] @ W1
//                 + cur[i,:] @ (Wr0+Wr1) + (b0+b1) )
// Tile: 64 rows x 128 cols per block (256 threads), thread = 4 rows x 8 cols.
// K processed as 3 sources x 4 chunks of 32.  Safe for in-place cur==out:
// a block reads only its own rows and writes them only at the end.
// ---------------------------------------------------------------------------
__global__ void gemm_kernel(const float* __restrict__ cur,
                            const float* __restrict__ msgA,
                            const float* __restrict__ msgB,
                            const float* __restrict__ invA,
                            const float* __restrict__ invB,
                            const float* __restrict__ W0,
                            const float* __restrict__ W1,
                            const float* __restrict__ Wr0,
                            const float* __restrict__ Wr1,
                            const float* __restrict__ b0,
                            const float* __restrict__ b1,
                            float* __restrict__ out,
                            int n, int apply_sigmoid) {
    __shared__ float As[32][68];     // A^T chunk: [k][row], pad 64->68 (16B-aligned rows)
    __shared__ float Ws[32][128];    // W chunk:   [k][col]

    const int t   = threadIdx.x;
    const int tr  = t >> 4;          // 0..15  (row group)
    const int tc  = t & 15;          // 0..15  (col group)
    const int row0 = blockIdx.x * 64;

    float acc[4][8];
#pragma unroll
    for (int r = 0; r < 4; ++r)
#pragma unroll
        for (int c = 0; c < 8; ++c) acc[r][c] = 0.f;

    for (int s = 0; s < 3; ++s) {
        const float* A   = (s == 0) ? msgA : ((s == 1) ? msgB : cur);
        const float* inv = (s == 0) ? invA : invB;  // unused for s==2
        for (int kc = 0; kc < 4; ++kc) {
            __syncthreads();
            // --- stage A^T: thread (k = t&31, rb = t>>5) loads rows rb+8i ---
            {
                const int k  = t & 31;
                const int rb = t >> 5;
#pragma unroll
                for (int i = 0; i < 8; ++i) {
                    const int r   = rb + 8 * i;
                    const int row = row0 + r;
                    float v = 0.f;
                    if (row < n) {
                        v = A[(size_t)row * D + kc * 32 + k];
                        if (s < 2) v *= inv[row];
                    }
                    As[k][r] = v;
                }
            }
            // --- stage W: thread (col = t&127, kb = t>>7) loads k rows kb+2i ---
            {
                const int col = t & 127;
                const int kb  = t >> 7;
#pragma unroll
                for (int i = 0; i < 16; ++i) {
                    const int kk   = kb + 2 * i;
                    const int krow = kc * 32 + kk;
                    float w;
                    if (s == 0)      w = W0[krow * D + col];
                    else if (s == 1) w = W1[krow * D + col];
                    else             w = Wr0[krow * D + col] + Wr1[krow * D + col];
                    Ws[kk][col] = w;
                }
            }
            __syncthreads();
            // --- compute: 32 k-steps, 4x8 outer product each ---
#pragma unroll 4
            for (int kk = 0; kk < 32; ++kk) {
                const float4 a  = *reinterpret_cast<const float4*>(&As[kk][tr * 4]);
                const float4 w0 = *reinterpret_cast<const float4*>(&Ws[kk][tc * 8]);
                const float4 w1 = *reinterpret_cast<const float4*>(&Ws[kk][tc * 8 + 4]);
                const float av[4] = {a.x, a.y, a.z, a.w};
                const float wv[8] = {w0.x, w0.y, w0.z, w0.w, w1.x, w1.y, w1.z, w1.w};
#pragma unroll
                for (int r = 0; r < 4; ++r)
#pragma unroll
                    for (int c = 0; c < 8; ++c)
                        acc[r][c] = fmaf(av[r], wv[c], acc[r][c]);
            }
        }
    }

    // --- epilogue: bias (+ sigmoid on last layer), coalesced float4 stores ---
    const int colbase = tc * 8;
    float bias[8];
#pragma unroll
    for (int c = 0; c < 8; ++c) bias[c] = b0[colbase + c] + b1[colbase + c];

#pragma unroll
    for (int r = 0; r < 4; ++r) {
        const int row = row0 + tr * 4 + r;
        if (row >= n) continue;
        float v[8];
#pragma unroll
        for (int c = 0; c < 8; ++c) {
            float x = acc[r][c] + bias[c];
            if (apply_sigmoid) x = 1.0f / (1.0f + expf(-x));
            v[c] = x;
        }
        float4* op = reinterpret_cast<float4*>(out + (size_t)row * D + colbase);
        op[0] = make_float4(v[0], v[1], v[2], v[3]);
        op[1] = make_float4(v[4], v[5], v[6], v[7]);
    }
}

// ---------------------------------------------------------------------------
extern "C" void kernel_launch(void* const* d_in, const int* in_sizes, int n_in,
                              void* d_out, int out_size, void* d_ws, size_t ws_size,
                              hipStream_t stream) {
    const float* x    = (const float*)d_in[0];
    // d_in[1] = h, unused by the forward pass
    const int*   ei_a = (const int*)d_in[2];   // [2, E]
    const int*   ei_b = (const int*)d_in[3];
    const float* Wl   = (const float*)d_in[4]; // [L, T, D, D]
    const float* bl   = (const float*)d_in[5]; // [L, T, D]
    const float* Wr   = (const float*)d_in[6]; // [L, T, D, D]
    float* out = (float*)d_out;

    // workspace: msgA, msgB [N,D]; degA, degB [N]  (51.6 MB total)
    float* ws   = (float*)d_ws;
    float* msgA = ws;
    float* msgB = msgA + (size_t)N_NODES * D;
    float* degA = msgB + (size_t)N_NODES * D;
    float* degB = degA + N_NODES;

    const int* srcA = ei_a;
    const int* dstA = ei_a + NE;
    const int* srcB = ei_b;
    const int* dstB = ei_b + NE;

    // degrees (feature-independent): compute once, turn into reciprocals
    hipMemsetAsync(degA, 0, 2 * (size_t)N_NODES * sizeof(float), stream);
    deg_kernel<<<(NE + 255) / 256, 256, 0, stream>>>(dstA, degA, NE);
    deg_kernel<<<(NE + 255) / 256, 256, 0, stream>>>(dstB, degB, NE);
    inv_kernel<<<(N_NODES + 255) / 256, 256, 0, stream>>>(degA, degB, N_NODES);

    const int scatter_grid = (NE * 32 + 255) / 256;   // 100000 blocks
    const int gemm_grid    = (N_NODES + 63) / 64;     // 782 blocks

    for (int l = 0; l < 2; ++l) {
        const float* curf = (l == 0) ? x : out;
        hipMemsetAsync(msgA, 0, 2ull * N_NODES * D * sizeof(float), stream);
        scatter_kernel<<<scatter_grid, 256, 0, stream>>>(curf, srcA, dstA, msgA, NE);
        scatter_kernel<<<scatter_grid, 256, 0, stream>>>(curf, srcB, dstB, msgB, NE);

        const float* W0  = Wl + ((size_t)l * 2 + 0) * D * D;
        const float* W1  = Wl + ((size_t)l * 2 + 1) * D * D;
        const float* Wr0 = Wr + ((size_t)l * 2 + 0) * D * D;
        const float* Wr1 = Wr + ((size_t)l * 2 + 1) * D * D;
        const float* b0  = bl + ((size_t)l * 2 + 0) * D;
        const float* b1  = bl + ((size_t)l * 2 + 1) * D;

        gemm_kernel<<<gemm_grid, 256, 0, stream>>>(
            curf, msgA, msgB, degA, degB, W0, W1, Wr0, Wr1, b0, b1,
            out, N_NODES, (l == 1) ? 1 : 0);
    }
}

// Round 2
// 940.844 us; speedup vs baseline: 6.0884x; 6.0884x over previous
//
#include <hip/hip_runtime.h>
#include <math.h>

#define N_NODES 50000
#define D 128
#define NE 800000
#define BLK_ROWS 64

// ---------------------------------------------------------------------------
// CSR build (once per call; feature-independent, reused by both layers)
// ---------------------------------------------------------------------------
__global__ void count2_kernel(const int* __restrict__ dstA, const int* __restrict__ dstB,
                              int* __restrict__ cntA, int* __restrict__ cntB, int E) {
    int e = blockIdx.x * blockDim.x + threadIdx.x;
    if (e < E) {
        atomicAdd(&cntA[dstA[e]], 1);
        atomicAdd(&cntB[dstB[e]], 1);
    }
}

// exclusive scan of cnt[0..n-1] -> ptr[0..n]; single block of 1024 per type.
__global__ void scan_kernel(const int* __restrict__ cntA, int* __restrict__ ptrA,
                            const int* __restrict__ cntB, int* __restrict__ ptrB, int n) {
    const int* cnt = blockIdx.x ? cntB : cntA;
    int* ptr       = blockIdx.x ? ptrB : ptrA;
    __shared__ int sums[1024];
    const int t = threadIdx.x;
    const int chunk = (n + 1023) >> 10;
    const int start = min(t * chunk, n);
    const int end   = min(start + chunk, n);
    int s = 0;
    for (int i = start; i < end; ++i) s += cnt[i];
    sums[t] = s;
    __syncthreads();
    for (int off = 1; off < 1024; off <<= 1) {
        int v = (t >= off) ? sums[t - off] : 0;
        __syncthreads();
        sums[t] += v;
        __syncthreads();
    }
    int run = sums[t] - s;              // exclusive base for this thread's chunk
    for (int i = start; i < end; ++i) { ptr[i] = run; run += cnt[i]; }
    if (end == n) ptr[n] = run;         // total (== E); all boundary threads agree
}

__global__ void initcur_kernel(const int* __restrict__ ptrA, const int* __restrict__ ptrB,
                               int* __restrict__ curA, int* __restrict__ curB, int n) {
    int i = blockIdx.x * blockDim.x + threadIdx.x;
    if (i < n) { curA[i] = ptrA[i]; curB[i] = ptrB[i]; }
}

__global__ void fill2_kernel(const int* __restrict__ srcA, const int* __restrict__ dstA,
                             const int* __restrict__ srcB, const int* __restrict__ dstB,
                             int* __restrict__ curA, int* __restrict__ curB,
                             int* __restrict__ idxA, int* __restrict__ idxB, int E) {
    int e = blockIdx.x * blockDim.x + threadIdx.x;
    if (e < E) {
        int sa = atomicAdd(&curA[dstA[e]], 1);
        idxA[sa] = srcA[e];
        int sb = atomicAdd(&curB[dstB[e]], 1);
        idxB[sb] = srcB[e];
    }
}

// ---------------------------------------------------------------------------
// fused aggregate + GEMM:
//   out[i,:] = act( meanA[i,:] @ W0 + meanB[i,:] @ W1
//                 + cur[i,:] @ (Wr0+Wr1) + (b0+b1) )
// Block = 64 rows x 128 cols, 256 threads, thread computes 4x8.
// Per source s: fill Ms[64][136] in LDS (s<2: CSR gather-mean; s==2: own rows),
// then 4 k-chunks of 32 with W staged in Ws[32][128].
// No atomics; cur never aliases out.
// ---------------------------------------------------------------------------
__global__ __launch_bounds__(256) void aggmm_kernel(
    const float* __restrict__ cur,
    const int* __restrict__ ptrA, const int* __restrict__ idxA,
    const int* __restrict__ ptrB, const int* __restrict__ idxB,
    const float* __restrict__ W0, const float* __restrict__ W1,
    const float* __restrict__ Wr0, const float* __restrict__ Wr1,
    const float* __restrict__ b0, const float* __restrict__ b1,
    float* __restrict__ out, int n, int act) {

    __shared__ float Ms[BLK_ROWS][D + 8];   // pitch 136: conflict-free column reads
    __shared__ float Ws[32][D];

    const int t    = threadIdx.x;
    const int tr   = t >> 4;                // 0..15 row group
    const int tc   = t & 15;                // 0..15 col group
    const int row0 = blockIdx.x * BLK_ROWS;

    float acc[4][8];
#pragma unroll
    for (int r = 0; r < 4; ++r)
#pragma unroll
        for (int c = 0; c < 8; ++c) acc[r][c] = 0.f;

    for (int s = 0; s < 3; ++s) {
        __syncthreads();                    // Ms readers from previous source done
        // ---- fill Ms ----
        const int grp  = t >> 5;            // 0..7
        const int lane = t & 31;
        if (s < 2) {
            const int* ptr = (s == 0) ? ptrA : ptrB;
            const int* idx = (s == 0) ? idxA : idxB;
            for (int r = grp; r < BLK_ROWS; r += 8) {
                const int node = row0 + r;
                float ax = 0.f, ay = 0.f, az = 0.f, aw = 0.f;
                float invd = 0.f;
                if (node < n) {
                    const int beg = ptr[node], fin = ptr[node + 1];
                    int e = beg;
                    for (; e + 4 <= fin; e += 4) {
                        const int s0 = idx[e], s1 = idx[e + 1], s2 = idx[e + 2], s3 = idx[e + 3];
                        const float4 v0 = *reinterpret_cast<const float4*>(cur + (size_t)s0 * D + lane * 4);
                        const float4 v1 = *reinterpret_cast<const float4*>(cur + (size_t)s1 * D + lane * 4);
                        const float4 v2 = *reinterpret_cast<const float4*>(cur + (size_t)s2 * D + lane * 4);
                        const float4 v3 = *reinterpret_cast<const float4*>(cur + (size_t)s3 * D + lane * 4);
                        ax += v0.x + v1.x + v2.x + v3.x;
                        ay += v0.y + v1.y + v2.y + v3.y;
                        az += v0.z + v1.z + v2.z + v3.z;
                        aw += v0.w + v1.w + v2.w + v3.w;
                    }
                    for (; e < fin; ++e) {
                        const int s0 = idx[e];
                        const float4 v0 = *reinterpret_cast<const float4*>(cur + (size_t)s0 * D + lane * 4);
                        ax += v0.x; ay += v0.y; az += v0.z; aw += v0.w;
                    }
                    invd = 1.0f / fmaxf((float)(fin - beg), 1.0f);
                }
                *reinterpret_cast<float4*>(&Ms[r][lane * 4]) =
                    make_float4(ax * invd, ay * invd, az * invd, aw * invd);
            }
        } else {
            for (int r = grp; r < BLK_ROWS; r += 8) {
                const int node = row0 + r;
                float4 v = make_float4(0.f, 0.f, 0.f, 0.f);
                if (node < n) v = *reinterpret_cast<const float4*>(cur + (size_t)node * D + lane * 4);
                *reinterpret_cast<float4*>(&Ms[r][lane * 4]) = v;
            }
        }
        // ---- 4 k-chunks of 32 ----
        for (int kc = 0; kc < 4; ++kc) {
            __syncthreads();                // Ms ready / previous Ws consumed
            {
                const int col = t & 127, kb = t >> 7;
#pragma unroll
                for (int i = 0; i < 16; ++i) {
                    const int kk   = kb + 2 * i;
                    const int krow = kc * 32 + kk;
                    float w;
                    if (s == 0)      w = W0[krow * D + col];
                    else if (s == 1) w = W1[krow * D + col];
                    else             w = Wr0[krow * D + col] + Wr1[krow * D + col];
                    Ws[kk][col] = w;
                }
            }
            __syncthreads();
#pragma unroll 8
            for (int kk = 0; kk < 32; ++kk) {
                const int kg = kc * 32 + kk;
                const float a0 = Ms[tr * 4 + 0][kg];
                const float a1 = Ms[tr * 4 + 1][kg];
                const float a2 = Ms[tr * 4 + 2][kg];
                const float a3 = Ms[tr * 4 + 3][kg];
                const float4 w0 = *reinterpret_cast<const float4*>(&Ws[kk][tc * 8]);
                const float4 w1 = *reinterpret_cast<const float4*>(&Ws[kk][tc * 8 + 4]);
                const float av[4] = {a0, a1, a2, a3};
                const float wv[8] = {w0.x, w0.y, w0.z, w0.w, w1.x, w1.y, w1.z, w1.w};
#pragma unroll
                for (int r = 0; r < 4; ++r)
#pragma unroll
                    for (int c = 0; c < 8; ++c)
                        acc[r][c] = fmaf(av[r], wv[c], acc[r][c]);
            }
        }
    }

    // ---- epilogue: bias (+ sigmoid), float4 stores ----
    const int colbase = tc * 8;
    float bias[8];
#pragma unroll
    for (int c = 0; c < 8; ++c) bias[c] = b0[colbase + c] + b1[colbase + c];

#pragma unroll
    for (int r = 0; r < 4; ++r) {
        const int row = row0 + tr * 4 + r;
        if (row >= n) continue;
        float v[8];
#pragma unroll
        for (int c = 0; c < 8; ++c) {
            float x = acc[r][c] + bias[c];
            if (act) x = 1.0f / (1.0f + expf(-x));
            v[c] = x;
        }
        float4* op = reinterpret_cast<float4*>(out + (size_t)row * D + colbase);
        op[0] = make_float4(v[0], v[1], v[2], v[3]);
        op[1] = make_float4(v[4], v[5], v[6], v[7]);
    }
}

// ---------------------------------------------------------------------------
extern "C" void kernel_launch(void* const* d_in, const int* in_sizes, int n_in,
                              void* d_out, int out_size, void* d_ws, size_t ws_size,
                              hipStream_t stream) {
    const float* x    = (const float*)d_in[0];
    const int*   ei_a = (const int*)d_in[2];   // [2, E]
    const int*   ei_b = (const int*)d_in[3];
    const float* Wl   = (const float*)d_in[4]; // [L, T, D, D]
    const float* bl   = (const float*)d_in[5]; // [L, T, D]
    const float* Wr   = (const float*)d_in[6]; // [L, T, D, D]
    float* out = (float*)d_out;

    // workspace layout (ints first, then 16B-aligned float buffer): ~33 MB
    int* ptrA = (int*)d_ws;                      // N+1
    int* ptrB = ptrA + (N_NODES + 1);            // N+1
    int* curA = ptrB + (N_NODES + 1);            // N
    int* curB = curA + N_NODES;                  // N
    int* idxA = curB + N_NODES;                  // E
    int* idxB = idxA + NE;                       // E
    size_t int_end = (size_t)(idxB + NE);
    float* msg = (float*)((int_end + 15) & ~(size_t)15);  // [N, D] layer-1 output

    const int* srcA = ei_a;
    const int* dstA = ei_a + NE;
    const int* srcB = ei_b;
    const int* dstB = ei_b + NE;

    // ---- CSR build (counts in curA/curB, then scan, then fill) ----
    hipMemsetAsync(curA, 0, 2ull * N_NODES * sizeof(int), stream);
    count2_kernel<<<(NE + 255) / 256, 256, 0, stream>>>(dstA, dstB, curA, curB, NE);
    scan_kernel<<<2, 1024, 0, stream>>>(curA, ptrA, curB, ptrB, N_NODES);
    initcur_kernel<<<(N_NODES + 255) / 256, 256, 0, stream>>>(ptrA, ptrB, curA, curB, N_NODES);
    fill2_kernel<<<(NE + 255) / 256, 256, 0, stream>>>(srcA, dstA, srcB, dstB,
                                                       curA, curB, idxA, idxB, NE);

    const int grid = (N_NODES + BLK_ROWS - 1) / BLK_ROWS;   // 782

    for (int l = 0; l < 2; ++l) {
        const float* curf = (l == 0) ? x : msg;
        float* outf       = (l == 0) ? msg : out;
        const float* W0  = Wl + ((size_t)l * 2 + 0) * D * D;
        const float* W1  = Wl + ((size_t)l * 2 + 1) * D * D;
        const float* Wr0 = Wr + ((size_t)l * 2 + 0) * D * D;
        const float* Wr1 = Wr + ((size_t)l * 2 + 1) * D * D;
        const float* b0  = bl + ((size_t)l * 2 + 0) * D;
        const float* b1  = bl + ((size_t)l * 2 + 1) * D;
        aggmm_kernel<<<grid, 256, 0, stream>>>(
            curf, ptrA, idxA, ptrB, idxB, W0, W1, Wr0, Wr1, b0, b1,
            outf, N_NODES, (l == 1) ? 1 : 0);
    }
}

// Round 3
// 778.592 us; speedup vs baseline: 7.3572x; 1.2084x over previous
//
#include <hip/hip_runtime.h>
#include <math.h>

#define N_NODES 50000
#define D 128
#define NE 800000

typedef unsigned int uint;

// ---- bf16 helpers (bit-level, RN-even) ----
__device__ __forceinline__ float bflo(uint w) {
    uint u = w << 16;
    union { uint u; float f; } c; c.u = u; return c.f;
}
__device__ __forceinline__ float bfhi(uint w) {
    uint u = w & 0xffff0000u;
    union { uint u; float f; } c; c.u = u; return c.f;
}
__device__ __forceinline__ uint fp2bf_rn(float f) {   // bf16 in low 16 bits
    union { float f; uint u; } c; c.f = f;
    return (c.u + 0x7fffu + ((c.u >> 16) & 1u)) >> 16;
}

// ---------------------------------------------------------------------------
// x (f32) -> featb (bf16)
// ---------------------------------------------------------------------------
__global__ void f2b_kernel(const float4* __restrict__ in, uint2* __restrict__ out, int n4) {
    int i = blockIdx.x * blockDim.x + threadIdx.x;
    if (i < n4) {
        float4 v = in[i];
        uint2 o;
        o.x = fp2bf_rn(v.x) | (fp2bf_rn(v.y) << 16);
        o.y = fp2bf_rn(v.z) | (fp2bf_rn(v.w) << 16);
        out[i] = o;
    }
}

// ---------------------------------------------------------------------------
// CSR build
// ---------------------------------------------------------------------------
__global__ void count2_kernel(const int* __restrict__ dstA, const int* __restrict__ dstB,
                              int* __restrict__ cntA, int* __restrict__ cntB, int E) {
    int e = blockIdx.x * blockDim.x + threadIdx.x;
    if (e < E) {
        atomicAdd(&cntA[dstA[e]], 1);
        atomicAdd(&cntB[dstB[e]], 1);
    }
}

// exclusive scan of cnt -> ptr[0..n] AND cur[0..n-1] (cnt may alias cur).
__global__ void scan_kernel(const int* cntA, int* ptrA, int* curA,
                            const int* cntB, int* ptrB, int* curB, int n) {
    const int* cnt = blockIdx.x ? cntB : cntA;
    int* ptr = blockIdx.x ? ptrB : ptrA;
    int* curp = blockIdx.x ? curB : curA;
    __shared__ int sums[1024];
    const int t = threadIdx.x;
    const int chunk = (n + 1023) >> 10;
    const int start = min(t * chunk, n);
    const int end   = min(start + chunk, n);
    int s = 0;
    for (int i = start; i < end; ++i) s += cnt[i];
    sums[t] = s;
    __syncthreads();
    for (int off = 1; off < 1024; off <<= 1) {
        int v = (t >= off) ? sums[t - off] : 0;
        __syncthreads();
        sums[t] += v;
        __syncthreads();
    }
    int run = sums[t] - s;
    for (int i = start; i < end; ++i) {
        int c = cnt[i];           // read before aliased write
        ptr[i] = run; curp[i] = run;
        run += c;
    }
    if (end == n) ptr[n] = run;
}

__global__ void fill2_kernel(const int* __restrict__ srcA, const int* __restrict__ dstA,
                             const int* __restrict__ srcB, const int* __restrict__ dstB,
                             int* __restrict__ curA, int* __restrict__ curB,
                             int* __restrict__ idxA, int* __restrict__ idxB, int E) {
    int e = blockIdx.x * blockDim.x + threadIdx.x;
    if (e < E) {
        int sa = atomicAdd(&curA[dstA[e]], 1);
        idxA[sa] = srcA[e];
        int sb = atomicAdd(&curB[dstB[e]], 1);
        idxB[sb] = srcB[e];
    }
}

// ---------------------------------------------------------------------------
// mean gather: one 16-lane cluster per (type,node) row; 16B bf16x8 per lane.
// Zero LDS, low VGPR -> high occupancy, many outstanding gathers.
// Grid covers 2*N tasks (A rows then B rows), 16 tasks per 256-thread block.
// ---------------------------------------------------------------------------
__global__ __launch_bounds__(256) void mean2_kernel(
    const uint4* __restrict__ featb,   // [N][16] (128 bf16/row)
    const int* __restrict__ ptrA, const int* __restrict__ idxA,
    const int* __restrict__ ptrB, const int* __restrict__ idxB,
    uint4* __restrict__ meanA, uint4* __restrict__ meanB) {
    const int t = threadIdx.x;
    const int cl = t >> 4, lane = t & 15;
    int task = blockIdx.x * 16 + cl;
    const int* ptr = ptrA; const int* idx = idxA; uint4* out = meanA;
    if (task >= N_NODES) { task -= N_NODES; ptr = ptrB; idx = idxB; out = meanB; }
    const int beg = ptr[task], fin = ptr[task + 1];
    float a[8] = {0.f,0.f,0.f,0.f,0.f,0.f,0.f,0.f};
#define ACC(v) { a[0]+=bflo(v.x); a[1]+=bfhi(v.x); a[2]+=bflo(v.y); a[3]+=bfhi(v.y); \
                 a[4]+=bflo(v.z); a[5]+=bfhi(v.z); a[6]+=bflo(v.w); a[7]+=bfhi(v.w); }
    int e = beg;
    for (; e + 4 <= fin; e += 4) {
        uint4 v0 = featb[(size_t)idx[e]     * 16 + lane];
        uint4 v1 = featb[(size_t)idx[e + 1] * 16 + lane];
        uint4 v2 = featb[(size_t)idx[e + 2] * 16 + lane];
        uint4 v3 = featb[(size_t)idx[e + 3] * 16 + lane];
        ACC(v0); ACC(v1); ACC(v2); ACC(v3);
    }
    for (; e < fin; ++e) {
        uint4 v0 = featb[(size_t)idx[e] * 16 + lane];
        ACC(v0);
    }
#undef ACC
    const float invd = 1.0f / fmaxf((float)(fin - beg), 1.0f);
    uint4 o;
    o.x = fp2bf_rn(a[0] * invd) | (fp2bf_rn(a[1] * invd) << 16);
    o.y = fp2bf_rn(a[2] * invd) | (fp2bf_rn(a[3] * invd) << 16);
    o.z = fp2bf_rn(a[4] * invd) | (fp2bf_rn(a[5] * invd) << 16);
    o.w = fp2bf_rn(a[6] * invd) | (fp2bf_rn(a[7] * invd) << 16);
    out[(size_t)task * 16 + lane] = o;
}

// ---------------------------------------------------------------------------
// GEMM: out[i,:] = act( meanA@W0 + meanB@W1 + self@(Wr0+Wr1) + (b0+b1) )
// A sources all bf16 [N][128]; W/bias/accumulate in f32.
// 64 rows x 128 cols per 256-thread block, thread = 4x8.
// Layer 1: writes bf16 in-place to featb (block-own rows only).
// Layer 2: writes f32 sigmoid to d_out.
// ---------------------------------------------------------------------------
#define MS_PITCH 132   // rows 4 apart -> bank offset 16 (2-way, free)
__global__ __launch_bounds__(256) void gemm3_kernel(
    const uint4* __restrict__ selfb,
    const uint4* __restrict__ meanA, const uint4* __restrict__ meanB,
    const float* __restrict__ W0, const float* __restrict__ W1,
    const float* __restrict__ Wr0, const float* __restrict__ Wr1,
    const float* __restrict__ b0, const float* __restrict__ b1,
    float* __restrict__ outf, uint4* __restrict__ outb, int act) {

    __shared__ float Ms[64][MS_PITCH];
    __shared__ float Ws[32][D];

    const int t   = threadIdx.x;
    const int tr  = t >> 4;
    const int tc  = t & 15;
    const int row0 = blockIdx.x * 64;

    float acc[4][8];
#pragma unroll
    for (int r = 0; r < 4; ++r)
#pragma unroll
        for (int c = 0; c < 8; ++c) acc[r][c] = 0.f;

    for (int s = 0; s < 3; ++s) {
        const uint4* A = (s == 0) ? meanA : ((s == 1) ? meanB : selfb);
        __syncthreads();                      // previous-source Ms readers done
        // ---- fill Ms: 1024 uint4 reads, 4 per thread ----
#pragma unroll
        for (int i = 0; i < 4; ++i) {
            const int id   = t + 256 * i;
            const int r    = id >> 4;
            const int lane = id & 15;
            const int row  = row0 + r;
            uint4 v = make_uint4(0, 0, 0, 0);
            if (row < N_NODES) v = A[(size_t)row * 16 + lane];
            float* mp = &Ms[r][lane * 8];
            mp[0] = bflo(v.x); mp[1] = bfhi(v.x);
            mp[2] = bflo(v.y); mp[3] = bfhi(v.y);
            mp[4] = bflo(v.z); mp[5] = bfhi(v.z);
            mp[6] = bflo(v.w); mp[7] = bfhi(v.w);
        }
        for (int kc = 0; kc < 4; ++kc) {
            __syncthreads();                  // Ms ready / prev Ws consumed
            {
                const int col = t & 127, kb = t >> 7;
#pragma unroll
                for (int i = 0; i < 16; ++i) {
                    const int kk   = kb + 2 * i;
                    const int krow = kc * 32 + kk;
                    float w;
                    if (s == 0)      w = W0[krow * D + col];
                    else if (s == 1) w = W1[krow * D + col];
                    else             w = Wr0[krow * D + col] + Wr1[krow * D + col];
                    Ws[kk][col] = w;
                }
            }
            __syncthreads();
#pragma unroll 8
            for (int kk = 0; kk < 32; ++kk) {
                const int kg = kc * 32 + kk;
                const float av[4] = { Ms[tr * 4 + 0][kg], Ms[tr * 4 + 1][kg],
                                      Ms[tr * 4 + 2][kg], Ms[tr * 4 + 3][kg] };
                const float4 w0 = *reinterpret_cast<const float4*>(&Ws[kk][tc * 8]);
                const float4 w1 = *reinterpret_cast<const float4*>(&Ws[kk][tc * 8 + 4]);
                const float wv[8] = {w0.x, w0.y, w0.z, w0.w, w1.x, w1.y, w1.z, w1.w};
#pragma unroll
                for (int r = 0; r < 4; ++r)
#pragma unroll
                    for (int c = 0; c < 8; ++c)
                        acc[r][c] = fmaf(av[r], wv[c], acc[r][c]);
            }
        }
    }

    // ---- epilogue ----
    const int colbase = tc * 8;
    float bias[8];
#pragma unroll
    for (int c = 0; c < 8; ++c) bias[c] = b0[colbase + c] + b1[colbase + c];

#pragma unroll
    for (int r = 0; r < 4; ++r) {
        const int row = row0 + tr * 4 + r;
        if (row >= N_NODES) continue;
        float v[8];
#pragma unroll
        for (int c = 0; c < 8; ++c) v[c] = acc[r][c] + bias[c];
        if (act) {
#pragma unroll
            for (int c = 0; c < 8; ++c) v[c] = 1.0f / (1.0f + expf(-v[c]));
            float4* op = reinterpret_cast<float4*>(outf + (size_t)row * D + colbase);
            op[0] = make_float4(v[0], v[1], v[2], v[3]);
            op[1] = make_float4(v[4], v[5], v[6], v[7]);
        } else {
            uint4 o;
            o.x = fp2bf_rn(v[0]) | (fp2bf_rn(v[1]) << 16);
            o.y = fp2bf_rn(v[2]) | (fp2bf_rn(v[3]) << 16);
            o.z = fp2bf_rn(v[4]) | (fp2bf_rn(v[5]) << 16);
            o.w = fp2bf_rn(v[6]) | (fp2bf_rn(v[7]) << 16);
            outb[(size_t)row * 16 + tc] = o;
        }
    }
}

// ---------------------------------------------------------------------------
extern "C" void kernel_launch(void* const* d_in, const int* in_sizes, int n_in,
                              void* d_out, int out_size, void* d_ws, size_t ws_size,
                              hipStream_t stream) {
    const float* x    = (const float*)d_in[0];
    const int*   ei_a = (const int*)d_in[2];
    const int*   ei_b = (const int*)d_in[3];
    const float* Wl   = (const float*)d_in[4];
    const float* bl   = (const float*)d_in[5];
    const float* Wr   = (const float*)d_in[6];
    float* out = (float*)d_out;

    // ---- workspace layout (~45.6 MB) ----
    int* ptrA = (int*)d_ws;                       // N+1
    int* ptrB = ptrA + (N_NODES + 1);             // N+1
    int* curA = ptrB + (N_NODES + 1);             // N   (also counts)
    int* curB = curA + N_NODES;                   // N
    int* idxA = curB + N_NODES;                   // E
    int* idxB = idxA + NE;                        // E
    size_t int_end = (size_t)(idxB + NE);
    uint4* featb = (uint4*)((int_end + 15) & ~(size_t)15);     // [N][16] bf16
    uint4* meanA = featb + (size_t)N_NODES * 16;
    uint4* meanB = meanA + (size_t)N_NODES * 16;

    const int* srcA = ei_a;
    const int* dstA = ei_a + NE;
    const int* srcB = ei_b;
    const int* dstB = ei_b + NE;

    // x -> bf16 features
    f2b_kernel<<<(N_NODES * D / 4 + 255) / 256, 256, 0, stream>>>(
        (const float4*)x, (uint2*)featb, N_NODES * D / 4);

    // CSR build
    hipMemsetAsync(curA, 0, 2ull * N_NODES * sizeof(int), stream);
    count2_kernel<<<(NE + 255) / 256, 256, 0, stream>>>(dstA, dstB, curA, curB, NE);
    scan_kernel<<<2, 1024, 0, stream>>>(curA, ptrA, curA, curB, ptrB, curB, N_NODES);
    fill2_kernel<<<(NE + 255) / 256, 256, 0, stream>>>(srcA, dstA, srcB, dstB,
                                                       curA, curB, idxA, idxB, NE);

    const int mean_grid = (2 * N_NODES) / 16;           // 6250
    const int gemm_grid = (N_NODES + 63) / 64;          // 782

    for (int l = 0; l < 2; ++l) {
        const float* W0  = Wl + ((size_t)l * 2 + 0) * D * D;
        const float* W1  = Wl + ((size_t)l * 2 + 1) * D * D;
        const float* Wr0 = Wr + ((size_t)l * 2 + 0) * D * D;
        const float* Wr1 = Wr + ((size_t)l * 2 + 1) * D * D;
        const float* b0  = bl + ((size_t)l * 2 + 0) * D;
        const float* b1  = bl + ((size_t)l * 2 + 1) * D;

        mean2_kernel<<<mean_grid, 256, 0, stream>>>(featb, ptrA, idxA, ptrB, idxB,
                                                    meanA, meanB);
        gemm3_kernel<<<gemm_grid, 256, 0, stream>>>(
            featb, meanA, meanB, W0, W1, Wr0, Wr1, b0, b1,
            (l == 1) ? out : nullptr, (l == 0) ? featb : nullptr, (l == 1) ? 1 : 0);
    }
}

// Round 4
// 482.161 us; speedup vs baseline: 11.8803x; 1.6148x over previous
//
#include <hip/hip_runtime.h>
#include <math.h>

#define N_NODES 50000
#define D 128
#define NE 800000

typedef unsigned int uint;
typedef unsigned short ushort;

using bf16x8 = __attribute__((ext_vector_type(8))) short;
using f32x4  = __attribute__((ext_vector_type(4))) float;

// ---- bf16 helpers (bit-level, RN-even) ----
__device__ __forceinline__ float bflo(uint w) {
    union { uint u; float f; } c; c.u = w << 16; return c.f;
}
__device__ __forceinline__ float bfhi(uint w) {
    union { uint u; float f; } c; c.u = w & 0xffff0000u; return c.f;
}
__device__ __forceinline__ uint fp2bf_rn(float f) {   // bf16 in low 16 bits
    union { float f; uint u; } c; c.f = f;
    return (c.u + 0x7fffu + ((c.u >> 16) & 1u)) >> 16;
}

// ---------------------------------------------------------------------------
// x (f32) -> featb (bf16)
// ---------------------------------------------------------------------------
__global__ void f2b_kernel(const float4* __restrict__ in, uint2* __restrict__ out, int n4) {
    int i = blockIdx.x * blockDim.x + threadIdx.x;
    if (i < n4) {
        float4 v = in[i];
        uint2 o;
        o.x = fp2bf_rn(v.x) | (fp2bf_rn(v.y) << 16);
        o.y = fp2bf_rn(v.z) | (fp2bf_rn(v.w) << 16);
        out[i] = o;
    }
}

// ---------------------------------------------------------------------------
// W pre-pack: Wpack[l][ks][n][kk] (bf16) = Bcat[l][ks*32+kk][n] where
// Bcat rows 0..127 = Wl[l,0], 128..255 = Wl[l,1], 256..383 = Wr[l,0]+Wr[l,1].
// Fragment-order so each B-frag is one contiguous 16B load.
// ---------------------------------------------------------------------------
__global__ void wprep_kernel(const float* __restrict__ Wl, const float* __restrict__ Wr,
                             ushort* __restrict__ Wpack) {
    int i = blockIdx.x * blockDim.x + threadIdx.x;   // [2][12][128][32]
    if (i >= 2 * 12 * 128 * 32) return;
    const int l   = i / 49152;
    const int rem = i % 49152;
    const int ks  = rem / 4096;
    const int n   = (rem % 4096) / 32;
    const int kk  = rem % 32;
    const int r   = ks * 32 + kk;      // 0..383
    float v;
    if (r < 128)       v = Wl[(((size_t)l * 2 + 0) * 128 + r) * 128 + n];
    else if (r < 256)  v = Wl[(((size_t)l * 2 + 1) * 128 + (r - 128)) * 128 + n];
    else               v = Wr[(((size_t)l * 2 + 0) * 128 + (r - 256)) * 128 + n]
                         + Wr[(((size_t)l * 2 + 1) * 128 + (r - 256)) * 128 + n];
    Wpack[i] = (ushort)fp2bf_rn(v);
}

// ---------------------------------------------------------------------------
// CSR build
// ---------------------------------------------------------------------------
__global__ void count2_kernel(const int* __restrict__ dstA, const int* __restrict__ dstB,
                              int* __restrict__ cntA, int* __restrict__ cntB, int E) {
    int e = blockIdx.x * blockDim.x + threadIdx.x;
    if (e < E) {
        atomicAdd(&cntA[dstA[e]], 1);
        atomicAdd(&cntB[dstB[e]], 1);
    }
}

// exclusive scan of cnt -> ptr[0..n] AND cur[0..n-1] (cnt may alias cur).
__global__ void scan_kernel(const int* cntA, int* ptrA, int* curA,
                            const int* cntB, int* ptrB, int* curB, int n) {
    const int* cnt = blockIdx.x ? cntB : cntA;
    int* ptr  = blockIdx.x ? ptrB : ptrA;
    int* curp = blockIdx.x ? curB : curA;
    __shared__ int sums[1024];
    const int t = threadIdx.x;
    const int chunk = (n + 1023) >> 10;
    const int start = min(t * chunk, n);
    const int end   = min(start + chunk, n);
    int s = 0;
    for (int i = start; i < end; ++i) s += cnt[i];
    sums[t] = s;
    __syncthreads();
    for (int off = 1; off < 1024; off <<= 1) {
        int v = (t >= off) ? sums[t - off] : 0;
        __syncthreads();
        sums[t] += v;
        __syncthreads();
    }
    int run = sums[t] - s;
    for (int i = start; i < end; ++i) {
        int c = cnt[i];           // read before aliased write
        ptr[i] = run; curp[i] = run;
        run += c;
    }
    if (end == n) ptr[n] = run;
}

__global__ void fill2_kernel(const int* __restrict__ srcA, const int* __restrict__ dstA,
                             const int* __restrict__ srcB, const int* __restrict__ dstB,
                             int* __restrict__ curA, int* __restrict__ curB,
                             int* __restrict__ idxA, int* __restrict__ idxB, int E) {
    int e = blockIdx.x * blockDim.x + threadIdx.x;
    if (e < E) {
        int sa = atomicAdd(&curA[dstA[e]], 1);
        idxA[sa] = srcA[e];
        int sb = atomicAdd(&curB[dstB[e]], 1);
        idxB[sb] = srcB[e];
    }
}

// ---------------------------------------------------------------------------
// mean gather: one 16-lane cluster per (type,node) row; 16B bf16x8 per lane.
// featb/means 256B-aligned -> each row is exactly two 128B cache lines.
// ---------------------------------------------------------------------------
__global__ __launch_bounds__(256) void mean2_kernel(
    const uint4* __restrict__ featb,   // [N][16] (128 bf16/row)
    const int* __restrict__ ptrA, const int* __restrict__ idxA,
    const int* __restrict__ ptrB, const int* __restrict__ idxB,
    uint4* __restrict__ meanA, uint4* __restrict__ meanB) {
    const int t = threadIdx.x;
    const int cl = t >> 4, lane = t & 15;
    int task = blockIdx.x * 16 + cl;
    const int* ptr = ptrA; const int* idx = idxA; uint4* out = meanA;
    if (task >= N_NODES) { task -= N_NODES; ptr = ptrB; idx = idxB; out = meanB; }
    const int beg = ptr[task], fin = ptr[task + 1];
    float a[8] = {0.f,0.f,0.f,0.f,0.f,0.f,0.f,0.f};
#define ACC(v) { a[0]+=bflo(v.x); a[1]+=bfhi(v.x); a[2]+=bflo(v.y); a[3]+=bfhi(v.y); \
                 a[4]+=bflo(v.z); a[5]+=bfhi(v.z); a[6]+=bflo(v.w); a[7]+=bfhi(v.w); }
    int e = beg;
    for (; e + 4 <= fin; e += 4) {
        uint4 v0 = featb[(size_t)idx[e]     * 16 + lane];
        uint4 v1 = featb[(size_t)idx[e + 1] * 16 + lane];
        uint4 v2 = featb[(size_t)idx[e + 2] * 16 + lane];
        uint4 v3 = featb[(size_t)idx[e + 3] * 16 + lane];
        ACC(v0); ACC(v1); ACC(v2); ACC(v3);
    }
    for (; e < fin; ++e) {
        uint4 v0 = featb[(size_t)idx[e] * 16 + lane];
        ACC(v0);
    }
#undef ACC
    const float invd = 1.0f / fmaxf((float)(fin - beg), 1.0f);
    uint4 o;
    o.x = fp2bf_rn(a[0] * invd) | (fp2bf_rn(a[1] * invd) << 16);
    o.y = fp2bf_rn(a[2] * invd) | (fp2bf_rn(a[3] * invd) << 16);
    o.z = fp2bf_rn(a[4] * invd) | (fp2bf_rn(a[5] * invd) << 16);
    o.w = fp2bf_rn(a[6] * invd) | (fp2bf_rn(a[7] * invd) << 16);
    out[(size_t)task * 16 + lane] = o;
}

// ---------------------------------------------------------------------------
// MFMA GEMM: out[i,:] = act( [meanA|meanB|self][i,:384] @ Bcat + b0+b1 )
// Block = 256 threads = 4 waves; wave = 32 rows x 128 cols.
// Zero LDS, zero barriers: A-frags and B-frags are direct 16B global loads
// (all operands L2/LLC-resident). K = 12 steps of 32, f32 accumulation.
// A and B use the SAME (group,elem)->k slot mapping, so the contraction is
// correct under k-permutation invariance; C/D layout: col=lane&15,
// row=(lane>>4)*4+reg (HW-verified).
// Layer 1 (act=0): bf16 store in-place to featb (wave writes only rows it
// read for the self term -> no cross-wave hazard). Layer 2: f32 sigmoid.
// ---------------------------------------------------------------------------
__global__ __launch_bounds__(256) void mfma_gemm_kernel(
    const ushort* __restrict__ meanA, const ushort* __restrict__ meanB,
    const ushort* __restrict__ selfb,
    const ushort* __restrict__ Wpack,  // [12][128][32] bf16 for this layer
    const float* __restrict__ b0, const float* __restrict__ b1,
    float* __restrict__ outf, ushort* __restrict__ outb, int act) {

    const int lane = threadIdx.x & 63;
    const int wid  = threadIdx.x >> 6;
    const int row0 = blockIdx.x * 128 + wid * 32;
    const int mrow = lane & 15;
    const int g    = lane >> 4;        // k-chunk of 8 within the 32-k step

    f32x4 acc[2][8];
#pragma unroll
    for (int mf = 0; mf < 2; ++mf)
#pragma unroll
        for (int nf = 0; nf < 8; ++nf) acc[mf][nf] = (f32x4){0.f, 0.f, 0.f, 0.f};

#pragma unroll
    for (int ks = 0; ks < 12; ++ks) {
        const int k0 = ks * 32;
        const ushort* A = (k0 < 128) ? meanA : ((k0 < 256) ? meanB : selfb);
        const int ak = k0 & 127;
        const bf16x8 a0 = *reinterpret_cast<const bf16x8*>(
            A + (size_t)(row0 + mrow) * D + ak + g * 8);
        const bf16x8 a1 = *reinterpret_cast<const bf16x8*>(
            A + (size_t)(row0 + 16 + mrow) * D + ak + g * 8);
        const ushort* Wk = Wpack + (size_t)ks * 128 * 32;
#pragma unroll
        for (int nf = 0; nf < 8; ++nf) {
            const bf16x8 b = *reinterpret_cast<const bf16x8*>(
                Wk + ((nf * 16 + mrow) * 32 + g * 8));
            acc[0][nf] = __builtin_amdgcn_mfma_f32_16x16x32_bf16(a0, b, acc[0][nf], 0, 0, 0);
            acc[1][nf] = __builtin_amdgcn_mfma_f32_16x16x32_bf16(a1, b, acc[1][nf], 0, 0, 0);
        }
    }

    // ---- epilogue ----
#pragma unroll
    for (int nf = 0; nf < 8; ++nf) {
        const int col  = nf * 16 + mrow;
        const float bias = b0[col] + b1[col];
#pragma unroll
        for (int mf = 0; mf < 2; ++mf) {
#pragma unroll
            for (int r = 0; r < 4; ++r) {
                const int row = row0 + mf * 16 + g * 4 + r;
                if (row < N_NODES) {
                    float v = acc[mf][nf][r] + bias;
                    if (act) {
                        v = 1.0f / (1.0f + expf(-v));
                        outf[(size_t)row * D + col] = v;
                    } else {
                        outb[(size_t)row * D + col] = (ushort)fp2bf_rn(v);
                    }
                }
            }
        }
    }
}

// ---------------------------------------------------------------------------
extern "C" void kernel_launch(void* const* d_in, const int* in_sizes, int n_in,
                              void* d_out, int out_size, void* d_ws, size_t ws_size,
                              hipStream_t stream) {
    const float* x    = (const float*)d_in[0];
    const int*   ei_a = (const int*)d_in[2];
    const int*   ei_b = (const int*)d_in[3];
    const float* Wl   = (const float*)d_in[4];
    const float* bl   = (const float*)d_in[5];
    const float* Wr   = (const float*)d_in[6];
    float* out = (float*)d_out;

    // ---- workspace: bf16 feature buffers FIRST (256B-aligned rows) ----
    ushort* featb = (ushort*)d_ws;                         // [N][128]
    ushort* meanA = featb + (size_t)N_NODES * D;           // [N][128]
    ushort* meanB = meanA + (size_t)N_NODES * D;           // [N][128]
    int* ptrA = (int*)(meanB + (size_t)N_NODES * D);       // N+1
    int* ptrB = ptrA + (N_NODES + 1);
    int* curA = ptrB + (N_NODES + 1);                      // N (also counts)
    int* curB = curA + N_NODES;
    int* idxA = curB + N_NODES;                            // E
    int* idxB = idxA + NE;                                 // E
    ushort* Wpack = (ushort*)(((size_t)(idxB + NE) + 63) & ~(size_t)63);  // [2][12][128][32]

    const int* srcA = ei_a;
    const int* dstA = ei_a + NE;
    const int* srcB = ei_b;
    const int* dstB = ei_b + NE;

    // feature cast + weight pack (independent, tiny)
    f2b_kernel<<<(N_NODES * D / 4 + 255) / 256, 256, 0, stream>>>(
        (const float4*)x, (uint2*)featb, N_NODES * D / 4);
    wprep_kernel<<<(2 * 12 * 128 * 32 + 255) / 256, 256, 0, stream>>>(Wl, Wr, Wpack);

    // CSR build
    hipMemsetAsync(curA, 0, 2ull * N_NODES * sizeof(int), stream);
    count2_kernel<<<(NE + 255) / 256, 256, 0, stream>>>(dstA, dstB, curA, curB, NE);
    scan_kernel<<<2, 1024, 0, stream>>>(curA, ptrA, curA, curB, ptrB, curB, N_NODES);
    fill2_kernel<<<(NE + 255) / 256, 256, 0, stream>>>(srcA, dstA, srcB, dstB,
                                                       curA, curB, idxA, idxB, NE);

    const int mean_grid = (2 * N_NODES) / 16;              // 6250
    const int gemm_grid = (N_NODES + 127) / 128;           // 391

    for (int l = 0; l < 2; ++l) {
        const float* b0 = bl + ((size_t)l * 2 + 0) * D;
        const float* b1 = bl + ((size_t)l * 2 + 1) * D;
        mean2_kernel<<<mean_grid, 256, 0, stream>>>((const uint4*)featb, ptrA, idxA,
                                                    ptrB, idxB, (uint4*)meanA, (uint4*)meanB);
        mfma_gemm_kernel<<<gemm_grid, 256, 0, stream>>>(
            meanA, meanB, featb, Wpack + (size_t)l * 12 * 128 * 32, b0, b1,
            (l == 1) ? out : nullptr, (l == 0) ? featb : nullptr, (l == 1) ? 1 : 0);
    }
}

// Round 5
// 233.849 us; speedup vs baseline: 24.4954x; 2.0619x over previous
//
#include <hip/hip_runtime.h>
#include <math.h>

#define N_NODES 50000
#define D 128
#define NE 800000
#define NB 512                 // nodes per bucket (dst >> 9)
#define NBUCK 98               // ceil(N_NODES / NB)
#define EPB 4096               // edges per partition/hist block
#define PBLK 196               // ceil(NE / EPB)

typedef unsigned int uint;
typedef unsigned short ushort;

using bf16x8 = __attribute__((ext_vector_type(8))) short;
using f32x4  = __attribute__((ext_vector_type(4))) float;

// ---- bf16 helpers (bit-level, RN-even) ----
__device__ __forceinline__ float bflo(uint w) {
    union { uint u; float f; } c; c.u = w << 16; return c.f;
}
__device__ __forceinline__ float bfhi(uint w) {
    union { uint u; float f; } c; c.u = w & 0xffff0000u; return c.f;
}
__device__ __forceinline__ uint fp2bf_rn(float f) {
    union { float f; uint u; } c; c.f = f;
    return (c.u + 0x7fffu + ((c.u >> 16) & 1u)) >> 16;
}

// ---------------------------------------------------------------------------
// x (f32) -> featb (bf16)
// ---------------------------------------------------------------------------
__global__ void f2b_kernel(const float4* __restrict__ in, uint2* __restrict__ out, int n4) {
    int i = blockIdx.x * blockDim.x + threadIdx.x;
    if (i < n4) {
        float4 v = in[i];
        uint2 o;
        o.x = fp2bf_rn(v.x) | (fp2bf_rn(v.y) << 16);
        o.y = fp2bf_rn(v.z) | (fp2bf_rn(v.w) << 16);
        out[i] = o;
    }
}

// ---------------------------------------------------------------------------
// W pre-pack: Wpack[l][ks][n][kk] (bf16), Bcat rows = Wl[l,0] | Wl[l,1] | Wr0+Wr1
// ---------------------------------------------------------------------------
__global__ void wprep_kernel(const float* __restrict__ Wl, const float* __restrict__ Wr,
                             ushort* __restrict__ Wpack) {
    int i = blockIdx.x * blockDim.x + threadIdx.x;   // [2][12][128][32]
    if (i >= 2 * 12 * 128 * 32) return;
    const int l   = i / 49152;
    const int rem = i % 49152;
    const int ks  = rem / 4096;
    const int n   = (rem % 4096) / 32;
    const int kk  = rem % 32;
    const int r   = ks * 32 + kk;      // 0..383
    float v;
    if (r < 128)       v = Wl[(((size_t)l * 2 + 0) * 128 + r) * 128 + n];
    else if (r < 256)  v = Wl[(((size_t)l * 2 + 1) * 128 + (r - 128)) * 128 + n];
    else               v = Wr[(((size_t)l * 2 + 0) * 128 + (r - 256)) * 128 + n]
                         + Wr[(((size_t)l * 2 + 1) * 128 + (r - 256)) * 128 + n];
    Wpack[i] = (ushort)fp2bf_rn(v);
}

// ---------------------------------------------------------------------------
// CSR build, bucketed.  Bucket b = dst >> 9 (NB=512 nodes each).
// ---------------------------------------------------------------------------
// 1) per-bucket edge histogram (LDS-aggregated)
__global__ __launch_bounds__(256) void hist_kernel(
    const int* __restrict__ dstA, const int* __restrict__ dstB,
    int* __restrict__ bhistA, int* __restrict__ bhistB) {
    __shared__ int h[NBUCK];
    const int t = threadIdx.x;
    const int typ = blockIdx.x >= PBLK;
    const int* dst = typ ? dstB : dstA;
    int* bh        = typ ? bhistB : bhistA;
    const int e0 = (blockIdx.x - (typ ? PBLK : 0)) * EPB;
    if (t < NBUCK) h[t] = 0;
    __syncthreads();
#pragma unroll
    for (int i = 0; i < EPB / 256; ++i) {
        const int e = e0 + t + i * 256;
        if (e < NE) atomicAdd(&h[dst[e] >> 9], 1);
    }
    __syncthreads();
    if (t < NBUCK && h[t]) atomicAdd(&bh[t], h[t]);
}

// 2) 98-element exclusive scan per type -> bucket bases + cursors; ptr[N]=NE
__global__ void bscan_kernel(const int* __restrict__ bhistA, int* __restrict__ bbaseA,
                             int* __restrict__ bcurA, int* __restrict__ ptrA,
                             const int* __restrict__ bhistB, int* __restrict__ bbaseB,
                             int* __restrict__ bcurB, int* __restrict__ ptrB) {
    const int* bh = blockIdx.x ? bhistB : bhistA;
    int* bb  = blockIdx.x ? bbaseB : bbaseA;
    int* bc  = blockIdx.x ? bcurB : bcurA;
    int* ptr = blockIdx.x ? ptrB : ptrA;
    __shared__ int s[128];
    const int t = threadIdx.x;       // 128 threads
    const int v = (t < NBUCK) ? bh[t] : 0;
    s[t] = v;
    __syncthreads();
    for (int off = 1; off < 128; off <<= 1) {
        int u = (t >= off) ? s[t - off] : 0;
        __syncthreads();
        s[t] += u;
        __syncthreads();
    }
    if (t < NBUCK) { const int ex = s[t] - v; bb[t] = ex; bc[t] = ex; }
    if (t == 0) ptr[N_NODES] = NE;
}

// 3) partition edges into bucket-contiguous record runs (block-aggregated)
__global__ __launch_bounds__(256) void part_kernel(
    const int* __restrict__ srcA, const int* __restrict__ dstA,
    const int* __restrict__ srcB, const int* __restrict__ dstB,
    int* __restrict__ bcurA, int* __restrict__ bcurB,
    uint* __restrict__ ebufA, uint* __restrict__ ebufB) {
    __shared__ int h[NBUCK];
    __shared__ int base[NBUCK];
    const int t = threadIdx.x;
    const int typ = blockIdx.x >= PBLK;
    const int* src = typ ? srcB : srcA;
    const int* dst = typ ? dstB : dstA;
    int* bc        = typ ? bcurB : bcurA;
    uint* ebuf     = typ ? ebufB : ebufA;
    const int e0 = (blockIdx.x - (typ ? PBLK : 0)) * EPB;
    if (t < NBUCK) h[t] = 0;
    __syncthreads();
#pragma unroll
    for (int i = 0; i < EPB / 256; ++i) {
        const int e = e0 + t + i * 256;
        if (e < NE) atomicAdd(&h[dst[e] >> 9], 1);
    }
    __syncthreads();
    if (t < NBUCK) {
        const int c = h[t];
        base[t] = c ? atomicAdd(&bc[t], c) : 0;
        h[t] = 0;                      // reuse as local cursor
    }
    __syncthreads();
#pragma unroll
    for (int i = 0; i < EPB / 256; ++i) {
        const int e = e0 + t + i * 256;
        if (e < NE) {
            const int d = dst[e];
            const int b = d >> 9;
            const int pos = atomicAdd(&h[b], 1);
            ebuf[base[b] + pos] = (uint)src[e] | ((uint)(d & 511) << 17);
        }
    }
}

// 4) per-bucket CSR fill: LDS per-node count -> LDS scan -> ptr + ushort idx
__global__ __launch_bounds__(256) void csrfill_kernel(
    const uint* __restrict__ ebufA, const int* __restrict__ bhistA,
    const int* __restrict__ bbaseA, int* __restrict__ ptrA, ushort* __restrict__ idxA,
    const uint* __restrict__ ebufB, const int* __restrict__ bhistB,
    const int* __restrict__ bbaseB, int* __restrict__ ptrB, ushort* __restrict__ idxB) {
    __shared__ int cnt[NB];
    __shared__ int lbase[NB];
    __shared__ int ps[256];
    const int t = threadIdx.x;
    int b = blockIdx.x;
    const int typ = b >= NBUCK;
    if (typ) b -= NBUCK;
    const uint* ebuf = typ ? ebufB : ebufA;
    const int count  = (typ ? bhistB : bhistA)[b];
    const int base   = (typ ? bbaseB : bbaseA)[b];
    int* ptr         = typ ? ptrB : ptrA;
    ushort* idx      = typ ? idxB : idxA;

    cnt[t] = 0; cnt[t + 256] = 0;
    __syncthreads();
    for (int e = t; e < count; e += 256)
        atomicAdd(&cnt[ebuf[base + e] >> 17], 1);
    __syncthreads();
    // exclusive scan of cnt[0..511]
    const int pair = cnt[2 * t] + cnt[2 * t + 1];
    ps[t] = pair;
    __syncthreads();
    for (int off = 1; off < 256; off <<= 1) {
        int u = (t >= off) ? ps[t - off] : 0;
        __syncthreads();
        ps[t] += u;
        __syncthreads();
    }
    const int ex = ps[t] - pair;
    lbase[2 * t]     = ex;
    lbase[2 * t + 1] = ex + cnt[2 * t];
    __syncthreads();
    // ptr slice (coalesced) + reset cnt as cursors
#pragma unroll
    for (int j = t; j < NB; j += 256) {
        const int node = b * NB + j;
        if (node < N_NODES) ptr[node] = base + lbase[j];
        cnt[j] = 0;
    }
    __syncthreads();
    for (int e = t; e < count; e += 256) {
        const uint rec = ebuf[base + e];
        const int local = rec >> 17;
        const int pos = atomicAdd(&cnt[local], 1);
        idx[base + lbase[local] + pos] = (ushort)(rec & 0x1FFFFu);
    }
}

// ---------------------------------------------------------------------------
// mean gather: 16-lane cluster per (type,node) row; 16B bf16x8 per lane.
// ---------------------------------------------------------------------------
__global__ __launch_bounds__(256) void mean2_kernel(
    const uint4* __restrict__ featb,   // [N][16] (128 bf16/row)
    const int* __restrict__ ptrA, const ushort* __restrict__ idxA,
    const int* __restrict__ ptrB, const ushort* __restrict__ idxB,
    uint4* __restrict__ meanA, uint4* __restrict__ meanB) {
    const int t = threadIdx.x;
    const int cl = t >> 4, lane = t & 15;
    int task = blockIdx.x * 16 + cl;
    const int* ptr = ptrA; const ushort* idx = idxA; uint4* out = meanA;
    if (task >= N_NODES) { task -= N_NODES; ptr = ptrB; idx = idxB; out = meanB; }
    const int beg = ptr[task], fin = ptr[task + 1];
    float a[8] = {0.f,0.f,0.f,0.f,0.f,0.f,0.f,0.f};
#define ACC(v) { a[0]+=bflo(v.x); a[1]+=bfhi(v.x); a[2]+=bflo(v.y); a[3]+=bfhi(v.y); \
                 a[4]+=bflo(v.z); a[5]+=bfhi(v.z); a[6]+=bflo(v.w); a[7]+=bfhi(v.w); }
    int e = beg;
    for (; e + 4 <= fin; e += 4) {
        uint4 v0 = featb[(size_t)idx[e]     * 16 + lane];
        uint4 v1 = featb[(size_t)idx[e + 1] * 16 + lane];
        uint4 v2 = featb[(size_t)idx[e + 2] * 16 + lane];
        uint4 v3 = featb[(size_t)idx[e + 3] * 16 + lane];
        ACC(v0); ACC(v1); ACC(v2); ACC(v3);
    }
    for (; e < fin; ++e) {
        uint4 v0 = featb[(size_t)idx[e] * 16 + lane];
        ACC(v0);
    }
#undef ACC
    const float invd = 1.0f / fmaxf((float)(fin - beg), 1.0f);
    uint4 o;
    o.x = fp2bf_rn(a[0] * invd) | (fp2bf_rn(a[1] * invd) << 16);
    o.y = fp2bf_rn(a[2] * invd) | (fp2bf_rn(a[3] * invd) << 16);
    o.z = fp2bf_rn(a[4] * invd) | (fp2bf_rn(a[5] * invd) << 16);
    o.w = fp2bf_rn(a[6] * invd) | (fp2bf_rn(a[7] * invd) << 16);
    out[(size_t)task * 16 + lane] = o;
}

// ---------------------------------------------------------------------------
// MFMA GEMM: out[i,:] = act( [meanA|meanB|self][i,:384] @ Bcat + b0+b1 )
// Wave = 32 rows x 128 cols; zero LDS; direct 16B global loads.
// ---------------------------------------------------------------------------
__global__ __launch_bounds__(256) void mfma_gemm_kernel(
    const ushort* __restrict__ meanA, const ushort* __restrict__ meanB,
    const ushort* __restrict__ selfb,
    const ushort* __restrict__ Wpack,  // [12][128][32] bf16 for this layer
    const float* __restrict__ b0, const float* __restrict__ b1,
    float* __restrict__ outf, ushort* __restrict__ outb, int act) {

    const int lane = threadIdx.x & 63;
    const int wid  = threadIdx.x >> 6;
    const int row0 = blockIdx.x * 128 + wid * 32;
    const int mrow = lane & 15;
    const int g    = lane >> 4;

    f32x4 acc[2][8];
#pragma unroll
    for (int mf = 0; mf < 2; ++mf)
#pragma unroll
        for (int nf = 0; nf < 8; ++nf) acc[mf][nf] = (f32x4){0.f, 0.f, 0.f, 0.f};

#pragma unroll
    for (int ks = 0; ks < 12; ++ks) {
        const int k0 = ks * 32;
        const ushort* A = (k0 < 128) ? meanA : ((k0 < 256) ? meanB : selfb);
        const int ak = k0 & 127;
        const bf16x8 a0 = *reinterpret_cast<const bf16x8*>(
            A + (size_t)(row0 + mrow) * D + ak + g * 8);
        const bf16x8 a1 = *reinterpret_cast<const bf16x8*>(
            A + (size_t)(row0 + 16 + mrow) * D + ak + g * 8);
        const ushort* Wk = Wpack + (size_t)ks * 128 * 32;
#pragma unroll
        for (int nf = 0; nf < 8; ++nf) {
            const bf16x8 b = *reinterpret_cast<const bf16x8*>(
                Wk + ((nf * 16 + mrow) * 32 + g * 8));
            acc[0][nf] = __builtin_amdgcn_mfma_f32_16x16x32_bf16(a0, b, acc[0][nf], 0, 0, 0);
            acc[1][nf] = __builtin_amdgcn_mfma_f32_16x16x32_bf16(a1, b, acc[1][nf], 0, 0, 0);
        }
    }

#pragma unroll
    for (int nf = 0; nf < 8; ++nf) {
        const int col  = nf * 16 + mrow;
        const float bias = b0[col] + b1[col];
#pragma unroll
        for (int mf = 0; mf < 2; ++mf) {
#pragma unroll
            for (int r = 0; r < 4; ++r) {
                const int row = row0 + mf * 16 + g * 4 + r;
                if (row < N_NODES) {
                    float v = acc[mf][nf][r] + bias;
                    if (act) {
                        v = 1.0f / (1.0f + expf(-v));
                        outf[(size_t)row * D + col] = v;
                    } else {
                        outb[(size_t)row * D + col] = (ushort)fp2bf_rn(v);
                    }
                }
            }
        }
    }
}

// ---------------------------------------------------------------------------
extern "C" void kernel_launch(void* const* d_in, const int* in_sizes, int n_in,
                              void* d_out, int out_size, void* d_ws, size_t ws_size,
                              hipStream_t stream) {
    const float* x    = (const float*)d_in[0];
    const int*   ei_a = (const int*)d_in[2];
    const int*   ei_b = (const int*)d_in[3];
    const float* Wl   = (const float*)d_in[4];
    const float* bl   = (const float*)d_in[5];
    const float* Wr   = (const float*)d_in[6];
    float* out = (float*)d_out;

    // ---- workspace layout (~48.6 MB) ----
    ushort* featb = (ushort*)d_ws;                          // [N][128]
    ushort* meanA = featb + (size_t)N_NODES * D;
    ushort* meanB = meanA + (size_t)N_NODES * D;
    int* ptrA  = (int*)(meanB + (size_t)N_NODES * D);       // N+1
    int* ptrB  = ptrA + (N_NODES + 1);                      // N+1
    uint* ebufA = (uint*)(ptrB + (N_NODES + 1));            // E
    uint* ebufB = ebufA + NE;                               // E
    ushort* idxA = (ushort*)(ebufB + NE);                   // E
    ushort* idxB = idxA + NE;                               // E
    int* bhistA = (int*)(idxB + NE);                        // 6 x NBUCK
    int* bhistB = bhistA + NBUCK;
    int* bbaseA = bhistB + NBUCK;
    int* bbaseB = bbaseA + NBUCK;
    int* bcurA  = bbaseB + NBUCK;
    int* bcurB  = bcurA + NBUCK;
    ushort* Wpack = (ushort*)(((size_t)(bcurB + NBUCK) + 63) & ~(size_t)63);

    const int* srcA = ei_a;
    const int* dstA = ei_a + NE;
    const int* srcB = ei_b;
    const int* dstB = ei_b + NE;

    // feature cast + weight pack
    f2b_kernel<<<(N_NODES * D / 4 + 255) / 256, 256, 0, stream>>>(
        (const float4*)x, (uint2*)featb, N_NODES * D / 4);
    wprep_kernel<<<(2 * 12 * 128 * 32 + 255) / 256, 256, 0, stream>>>(Wl, Wr, Wpack);

    // bucketed CSR build
    hipMemsetAsync(bhistA, 0, 2ull * NBUCK * sizeof(int), stream);
    hist_kernel<<<2 * PBLK, 256, 0, stream>>>(dstA, dstB, bhistA, bhistB);
    bscan_kernel<<<2, 128, 0, stream>>>(bhistA, bbaseA, bcurA, ptrA,
                                        bhistB, bbaseB, bcurB, ptrB);
    part_kernel<<<2 * PBLK, 256, 0, stream>>>(srcA, dstA, srcB, dstB,
                                              bcurA, bcurB, ebufA, ebufB);
    csrfill_kernel<<<2 * NBUCK, 256, 0, stream>>>(ebufA, bhistA, bbaseA, ptrA, idxA,
                                                  ebufB, bhistB, bbaseB, ptrB, idxB);

    const int mean_grid = (2 * N_NODES) / 16;               // 6250
    const int gemm_grid = (N_NODES + 127) / 128;            // 391

    for (int l = 0; l < 2; ++l) {
        const float* b0 = bl + ((size_t)l * 2 + 0) * D;
        const float* b1 = bl + ((size_t)l * 2 + 1) * D;
        mean2_kernel<<<mean_grid, 256, 0, stream>>>((const uint4*)featb, ptrA, idxA,
                                                    ptrB, idxB, (uint4*)meanA, (uint4*)meanB);
        mfma_gemm_kernel<<<gemm_grid, 256, 0, stream>>>(
            meanA, meanB, featb, Wpack + (size_t)l * 12 * 128 * 32, b0, b1,
            (l == 1) ? out : nullptr, (l == 0) ? featb : nullptr, (l == 1) ? 1 : 0);
    }
}

// Round 6
// 220.640 us; speedup vs baseline: 25.9618x; 1.0599x over previous
//
#include <hip/hip_runtime.h>
#include <math.h>

#define N_NODES 50000
#define D 128
#define NE 800000
#define NB 512                 // nodes per bucket (dst >> 9)
#define NBUCK 98               // ceil(N_NODES / NB)
#define CAP 10240              // slots per bucket (mean 8163, sigma ~90 -> 23 sigma)
#define EPB 4096               // edges per partition block
#define PBLK 196               // ceil(NE / EPB)

typedef unsigned int uint;
typedef unsigned short ushort;

using bf16x8 = __attribute__((ext_vector_type(8))) short;
using f32x4  = __attribute__((ext_vector_type(4))) float;

// ---- bf16 helpers (bit-level, RN-even) ----
__device__ __forceinline__ float bflo(uint w) {
    union { uint u; float f; } c; c.u = w << 16; return c.f;
}
__device__ __forceinline__ float bfhi(uint w) {
    union { uint u; float f; } c; c.u = w & 0xffff0000u; return c.f;
}
__device__ __forceinline__ uint fp2bf_rn(float f) {
    union { float f; uint u; } c; c.f = f;
    return (c.u + 0x7fffu + ((c.u >> 16) & 1u)) >> 16;
}

// ---------------------------------------------------------------------------
// prep: [0,6250) f2b cast; [6250,6634) W pre-pack; last block zeros cursors.
// Wpack[l][ks][n][kk] (bf16), Bcat rows = Wl[l,0] | Wl[l,1] | Wr0+Wr1.
// ---------------------------------------------------------------------------
#define F2B_BLKS 6250          // N*D/4 / 256
#define WPREP_BLKS 384         // 2*12*128*32 / 256
__global__ __launch_bounds__(256) void prep_kernel(
    const float4* __restrict__ x4, uint2* __restrict__ featb2,
    const float* __restrict__ Wl, const float* __restrict__ Wr,
    ushort* __restrict__ Wpack, int* __restrict__ bcurA, int* __restrict__ bcurB) {
    const int b = blockIdx.x;
    const int t = threadIdx.x;
    if (b < F2B_BLKS) {
        const int i = b * 256 + t;
        float4 v = x4[i];
        uint2 o;
        o.x = fp2bf_rn(v.x) | (fp2bf_rn(v.y) << 16);
        o.y = fp2bf_rn(v.z) | (fp2bf_rn(v.w) << 16);
        featb2[i] = o;
    } else if (b < F2B_BLKS + WPREP_BLKS) {
        const int i   = (b - F2B_BLKS) * 256 + t;   // [2][12][128][32]
        const int l   = i / 49152;
        const int rem = i % 49152;
        const int ks  = rem / 4096;
        const int n   = (rem % 4096) / 32;
        const int kk  = rem % 32;
        const int r   = ks * 32 + kk;
        float v;
        if (r < 128)       v = Wl[(((size_t)l * 2 + 0) * 128 + r) * 128 + n];
        else if (r < 256)  v = Wl[(((size_t)l * 2 + 1) * 128 + (r - 128)) * 128 + n];
        else               v = Wr[(((size_t)l * 2 + 0) * 128 + (r - 256)) * 128 + n]
                             + Wr[(((size_t)l * 2 + 1) * 128 + (r - 256)) * 128 + n];
        Wpack[i] = (ushort)fp2bf_rn(v);
    } else {
        if (t < NBUCK) { bcurA[t] = 0; bcurB[t] = 0; }
    }
}

// ---------------------------------------------------------------------------
// partition edges into fixed-capacity bucket regions (block-aggregated
// reservation: one global atomic per (block,bucket)).
// rec = src | (dst&511)<<17.  After this kernel bcur[b] = bucket edge count.
// ---------------------------------------------------------------------------
__global__ __launch_bounds__(256) void part_kernel(
    const int* __restrict__ srcA, const int* __restrict__ dstA,
    const int* __restrict__ srcB, const int* __restrict__ dstB,
    int* __restrict__ bcurA, int* __restrict__ bcurB,
    uint* __restrict__ ebufA, uint* __restrict__ ebufB) {
    __shared__ int h[NBUCK];
    __shared__ int base[NBUCK];
    const int t = threadIdx.x;
    const int typ = blockIdx.x >= PBLK;
    const int* src = typ ? srcB : srcA;
    const int* dst = typ ? dstB : dstA;
    int* bc        = typ ? bcurB : bcurA;
    uint* ebuf     = typ ? ebufB : ebufA;
    const int e0 = (blockIdx.x - (typ ? PBLK : 0)) * EPB;
    if (t < NBUCK) h[t] = 0;
    __syncthreads();
#pragma unroll
    for (int i = 0; i < EPB / 256; ++i) {
        const int e = e0 + t + i * 256;
        if (e < NE) atomicAdd(&h[dst[e] >> 9], 1);
    }
    __syncthreads();
    if (t < NBUCK) {
        const int c = h[t];
        base[t] = c ? atomicAdd(&bc[t], c) : 0;
        h[t] = 0;                      // reuse as local cursor
    }
    __syncthreads();
#pragma unroll
    for (int i = 0; i < EPB / 256; ++i) {
        const int e = e0 + t + i * 256;
        if (e < NE) {
            const int d = dst[e];
            const int b = d >> 9;
            const int pos = atomicAdd(&h[b], 1);
            ebuf[(size_t)b * CAP + base[b] + pos] = (uint)src[e] | ((uint)(d & 511) << 17);
        }
    }
}

// ---------------------------------------------------------------------------
// per-bucket CSR fill: LDS per-node count -> LDS scan -> pbeg/pend + ushort idx
// ---------------------------------------------------------------------------
__global__ __launch_bounds__(256) void csrfill_kernel(
    const uint* __restrict__ ebufA, const int* __restrict__ bcntA,
    int* __restrict__ pbegA, int* __restrict__ pendA, ushort* __restrict__ idxA,
    const uint* __restrict__ ebufB, const int* __restrict__ bcntB,
    int* __restrict__ pbegB, int* __restrict__ pendB, ushort* __restrict__ idxB) {
    __shared__ int cnt[NB];
    __shared__ int lbase[NB];
    __shared__ int ps[256];
    const int t = threadIdx.x;
    int b = blockIdx.x;
    const int typ = b >= NBUCK;
    if (typ) b -= NBUCK;
    const uint* ebuf = (typ ? ebufB : ebufA) + (size_t)b * CAP;
    const int count  = (typ ? bcntB : bcntA)[b];
    int* pbeg        = typ ? pbegB : pbegA;
    int* pend        = typ ? pendB : pendA;
    ushort* idx      = (typ ? idxB : idxA) + (size_t)b * CAP;

    cnt[t] = 0; cnt[t + 256] = 0;
    __syncthreads();
    for (int e = t; e < count; e += 256)
        atomicAdd(&cnt[ebuf[e] >> 17], 1);
    __syncthreads();
    // exclusive scan of cnt[0..511]
    const int pair = cnt[2 * t] + cnt[2 * t + 1];
    ps[t] = pair;
    __syncthreads();
    for (int off = 1; off < 256; off <<= 1) {
        int u = (t >= off) ? ps[t - off] : 0;
        __syncthreads();
        ps[t] += u;
        __syncthreads();
    }
    const int ex = ps[t] - pair;
    lbase[2 * t]     = ex;
    lbase[2 * t + 1] = ex + cnt[2 * t];
    __syncthreads();
    // pbeg/pend (coalesced) + reset cnt as cursors
#pragma unroll
    for (int j = t; j < NB; j += 256) {
        const int node = b * NB + j;
        if (node < N_NODES) {
            const int bs = b * CAP + lbase[j];
            pbeg[node] = bs;
            pend[node] = bs + cnt[j];
        }
        cnt[j] = 0;
    }
    __syncthreads();
    for (int e = t; e < count; e += 256) {
        const uint rec = ebuf[e];
        const int local = rec >> 17;
        const int pos = atomicAdd(&cnt[local], 1);
        idx[lbase[local] + pos] = (ushort)(rec & 0x1FFFFu);
    }
}

// ---------------------------------------------------------------------------
// mean gather: 16-lane cluster per (type,node) row; 16B bf16x8 per lane;
// 8 gathers in flight per lane.
// ---------------------------------------------------------------------------
__global__ __launch_bounds__(256) void mean2_kernel(
    const uint4* __restrict__ featb,   // [N][16] (128 bf16/row)
    const int* __restrict__ pbegA, const int* __restrict__ pendA,
    const ushort* __restrict__ idxA,
    const int* __restrict__ pbegB, const int* __restrict__ pendB,
    const ushort* __restrict__ idxB,
    uint4* __restrict__ meanA, uint4* __restrict__ meanB) {
    const int t = threadIdx.x;
    const int cl = t >> 4, lane = t & 15;
    int task = blockIdx.x * 16 + cl;
    const int* pbeg = pbegA; const int* pend = pendA;
    const ushort* idx = idxA; uint4* out = meanA;
    if (task >= N_NODES) {
        task -= N_NODES; pbeg = pbegB; pend = pendB; idx = idxB; out = meanB;
    }
    const int beg = pbeg[task], fin = pend[task];
    float a[8] = {0.f,0.f,0.f,0.f,0.f,0.f,0.f,0.f};
#define ACC(v) { a[0]+=bflo(v.x); a[1]+=bfhi(v.x); a[2]+=bflo(v.y); a[3]+=bfhi(v.y); \
                 a[4]+=bflo(v.z); a[5]+=bfhi(v.z); a[6]+=bflo(v.w); a[7]+=bfhi(v.w); }
    int e = beg;
    for (; e + 8 <= fin; e += 8) {
        uint4 v0 = featb[(size_t)idx[e]     * 16 + lane];
        uint4 v1 = featb[(size_t)idx[e + 1] * 16 + lane];
        uint4 v2 = featb[(size_t)idx[e + 2] * 16 + lane];
        uint4 v3 = featb[(size_t)idx[e + 3] * 16 + lane];
        uint4 v4 = featb[(size_t)idx[e + 4] * 16 + lane];
        uint4 v5 = featb[(size_t)idx[e + 5] * 16 + lane];
        uint4 v6 = featb[(size_t)idx[e + 6] * 16 + lane];
        uint4 v7 = featb[(size_t)idx[e + 7] * 16 + lane];
        ACC(v0); ACC(v1); ACC(v2); ACC(v3);
        ACC(v4); ACC(v5); ACC(v6); ACC(v7);
    }
    if (e + 4 <= fin) {
        uint4 v0 = featb[(size_t)idx[e]     * 16 + lane];
        uint4 v1 = featb[(size_t)idx[e + 1] * 16 + lane];
        uint4 v2 = featb[(size_t)idx[e + 2] * 16 + lane];
        uint4 v3 = featb[(size_t)idx[e + 3] * 16 + lane];
        ACC(v0); ACC(v1); ACC(v2); ACC(v3);
        e += 4;
    }
    for (; e < fin; ++e) {
        uint4 v0 = featb[(size_t)idx[e] * 16 + lane];
        ACC(v0);
    }
#undef ACC
    const float invd = 1.0f / fmaxf((float)(fin - beg), 1.0f);
    uint4 o;
    o.x = fp2bf_rn(a[0] * invd) | (fp2bf_rn(a[1] * invd) << 16);
    o.y = fp2bf_rn(a[2] * invd) | (fp2bf_rn(a[3] * invd) << 16);
    o.z = fp2bf_rn(a[4] * invd) | (fp2bf_rn(a[5] * invd) << 16);
    o.w = fp2bf_rn(a[6] * invd) | (fp2bf_rn(a[7] * invd) << 16);
    out[(size_t)task * 16 + lane] = o;
}

// ---------------------------------------------------------------------------
// MFMA GEMM: out[i,:] = act( [meanA|meanB|self][i,:384] @ Bcat + b0+b1 )
// Wave = 32 rows x 128 cols; zero LDS; direct 16B global loads.
// ---------------------------------------------------------------------------
__global__ __launch_bounds__(256) void mfma_gemm_kernel(
    const ushort* __restrict__ meanA, const ushort* __restrict__ meanB,
    const ushort* __restrict__ selfb,
    const ushort* __restrict__ Wpack,  // [12][128][32] bf16 for this layer
    const float* __restrict__ b0, const float* __restrict__ b1,
    float* __restrict__ outf, ushort* __restrict__ outb, int act) {

    const int lane = threadIdx.x & 63;
    const int wid  = threadIdx.x >> 6;
    const int row0 = blockIdx.x * 128 + wid * 32;
    const int mrow = lane & 15;
    const int g    = lane >> 4;

    f32x4 acc[2][8];
#pragma unroll
    for (int mf = 0; mf < 2; ++mf)
#pragma unroll
        for (int nf = 0; nf < 8; ++nf) acc[mf][nf] = (f32x4){0.f, 0.f, 0.f, 0.f};

#pragma unroll
    for (int ks = 0; ks < 12; ++ks) {
        const int k0 = ks * 32;
        const ushort* A = (k0 < 128) ? meanA : ((k0 < 256) ? meanB : selfb);
        const int ak = k0 & 127;
        const bf16x8 a0 = *reinterpret_cast<const bf16x8*>(
            A + (size_t)(row0 + mrow) * D + ak + g * 8);
        const bf16x8 a1 = *reinterpret_cast<const bf16x8*>(
            A + (size_t)(row0 + 16 + mrow) * D + ak + g * 8);
        const ushort* Wk = Wpack + (size_t)ks * 128 * 32;
#pragma unroll
        for (int nf = 0; nf < 8; ++nf) {
            const bf16x8 b = *reinterpret_cast<const bf16x8*>(
                Wk + ((nf * 16 + mrow) * 32 + g * 8));
            acc[0][nf] = __builtin_amdgcn_mfma_f32_16x16x32_bf16(a0, b, acc[0][nf], 0, 0, 0);
            acc[1][nf] = __builtin_amdgcn_mfma_f32_16x16x32_bf16(a1, b, acc[1][nf], 0, 0, 0);
        }
    }

#pragma unroll
    for (int nf = 0; nf < 8; ++nf) {
        const int col  = nf * 16 + mrow;
        const float bias = b0[col] + b1[col];
#pragma unroll
        for (int mf = 0; mf < 2; ++mf) {
#pragma unroll
            for (int r = 0; r < 4; ++r) {
                const int row = row0 + mf * 16 + g * 4 + r;
                if (row < N_NODES) {
                    float v = acc[mf][nf][r] + bias;
                    if (act) {
                        v = 1.0f / (1.0f + expf(-v));
                        outf[(size_t)row * D + col] = v;
                    } else {
                        outb[(size_t)row * D + col] = (ushort)fp2bf_rn(v);
                    }
                }
            }
        }
    }
}

// ---------------------------------------------------------------------------
extern "C" void kernel_launch(void* const* d_in, const int* in_sizes, int n_in,
                              void* d_out, int out_size, void* d_ws, size_t ws_size,
                              hipStream_t stream) {
    const float* x    = (const float*)d_in[0];
    const int*   ei_a = (const int*)d_in[2];
    const int*   ei_b = (const int*)d_in[3];
    const float* Wl   = (const float*)d_in[4];
    const float* bl   = (const float*)d_in[5];
    const float* Wr   = (const float*)d_in[6];
    float* out = (float*)d_out;

    // ---- workspace layout (~51.4 MB, within the 51.6 MB proven in R1) ----
    ushort* featb = (ushort*)d_ws;                          // [N][128]
    ushort* meanA = featb + (size_t)N_NODES * D;
    ushort* meanB = meanA + (size_t)N_NODES * D;
    uint* ebufA = (uint*)(meanB + (size_t)N_NODES * D);     // NBUCK*CAP
    uint* ebufB = ebufA + (size_t)NBUCK * CAP;              // NBUCK*CAP
    ushort* idxA = (ushort*)(ebufB + (size_t)NBUCK * CAP);  // NBUCK*CAP
    ushort* idxB = idxA + (size_t)NBUCK * CAP;              // NBUCK*CAP
    int* pbegA = (int*)(idxB + (size_t)NBUCK * CAP);        // N
    int* pendA = pbegA + N_NODES;
    int* pbegB = pendA + N_NODES;
    int* pendB = pbegB + N_NODES;
    int* bcurA = pendB + N_NODES;                           // NBUCK
    int* bcurB = bcurA + NBUCK;
    ushort* Wpack = (ushort*)(((size_t)(bcurB + NBUCK) + 63) & ~(size_t)63);

    const int* srcA = ei_a;
    const int* dstA = ei_a + NE;
    const int* srcB = ei_b;
    const int* dstB = ei_b + NE;

    prep_kernel<<<F2B_BLKS + WPREP_BLKS + 1, 256, 0, stream>>>(
        (const float4*)x, (uint2*)featb, Wl, Wr, Wpack, bcurA, bcurB);
    part_kernel<<<2 * PBLK, 256, 0, stream>>>(srcA, dstA, srcB, dstB,
                                              bcurA, bcurB, ebufA, ebufB);
    csrfill_kernel<<<2 * NBUCK, 256, 0, stream>>>(
        ebufA, bcurA, pbegA, pendA, idxA,
        ebufB, bcurB, pbegB, pendB, idxB);

    const int mean_grid = (2 * N_NODES) / 16;               // 6250
    const int gemm_grid = (N_NODES + 127) / 128;            // 391

    for (int l = 0; l < 2; ++l) {
        const float* b0 = bl + ((size_t)l * 2 + 0) * D;
        const float* b1 = bl + ((size_t)l * 2 + 1) * D;
        mean2_kernel<<<mean_grid, 256, 0, stream>>>(
            (const uint4*)featb, pbegA, pendA, idxA, pbegB, pendB, idxB,
            (uint4*)meanA, (uint4*)meanB);
        mfma_gemm_kernel<<<gemm_grid, 256, 0, stream>>>(
            meanA, meanB, featb, Wpack + (size_t)l * 12 * 128 * 32, b0, b1,
            (l == 1) ? out : nullptr, (l == 0) ? featb : nullptr, (l == 1) ? 1 : 0);
    }
}